// Round 2
// baseline (2076.428 us; speedup 1.0000x reference)
//
#include <hip/hip_runtime.h>
#include <math.h>

typedef unsigned short u16;
typedef unsigned int u32;
typedef short short8 __attribute__((ext_vector_type(8)));
typedef float f32x4 __attribute__((ext_vector_type(4)));

#define B_ 8
#define S_ 2048
#define D_ 512
#define N_ (B_ * S_)
#define ND_ ((size_t)N_ * D_)

__device__ __forceinline__ u16 f2bf(float f) {
  union { float f; u32 i; } v; v.f = f;
  u32 i = v.i;
  i += 0x7FFFu + ((i >> 16) & 1u);   // round-to-nearest-even
  return (u16)(i >> 16);
}
__device__ __forceinline__ float sigm(float x) { return 1.0f / (1.0f + expf(-x)); }

// ---------------------------------------------------------------------------
// f32 -> bf16 conversion (x and weight matrices), n % 4 == 0
// ---------------------------------------------------------------------------
__global__ __launch_bounds__(256) void cvt_bf16(const float* __restrict__ s,
                                                u16* __restrict__ d, int n)
{
  const int i = (blockIdx.x * 256 + threadIdx.x) * 4;
  if (i < n) {
    const float4 v = *(const float4*)(s + i);
    ushort4 o;
    o.x = f2bf(v.x); o.y = f2bf(v.y); o.z = f2bf(v.z); o.w = f2bf(v.w);
    *(ushort4*)(d + i) = o;
  }
}

// ---------------------------------------------------------------------------
// GEMM: out[m,n] = sum_k A[m,k]*W[n,k] + bias[n]; A Mx512 bf16, W 512x512 bf16,
// bias f32, out f32. 128x128 tile, BK=32, mfma_f32_16x16x32_bf16.
// ---------------------------------------------------------------------------
__global__ __launch_bounds__(256) void gemm_bt(
    const u16* __restrict__ A, const u16* __restrict__ W,
    const float* __restrict__ bias, float* __restrict__ out)
{
  __shared__ u16 As[128 * 40];
  __shared__ u16 Bs[128 * 40];
  const int tid = threadIdx.x;
  const int lane = tid & 63, wave = tid >> 6;
  const int wm = (wave >> 1) * 64, wn = (wave & 1) * 64;
  const int l15 = lane & 15, quad = lane >> 4;
  const int m0 = blockIdx.x * 128, n0 = blockIdx.y * 128;
  const int r0 = tid >> 2;
  const int kc0 = (tid & 3) * 8;

  f32x4 acc[4][4];
#pragma unroll
  for (int i = 0; i < 4; i++)
#pragma unroll
    for (int j = 0; j < 4; j++) acc[i][j] = (f32x4){0.f, 0.f, 0.f, 0.f};

  for (int k0 = 0; k0 < 512; k0 += 32) {
    uint4 a0 = *(const uint4*)(A + (size_t)(m0 + r0) * 512 + k0 + kc0);
    uint4 a1 = *(const uint4*)(A + (size_t)(m0 + r0 + 64) * 512 + k0 + kc0);
    uint4 b0 = *(const uint4*)(W + (size_t)(n0 + r0) * 512 + k0 + kc0);
    uint4 b1 = *(const uint4*)(W + (size_t)(n0 + r0 + 64) * 512 + k0 + kc0);
    __syncthreads();
    *(uint4*)(As + r0 * 40 + kc0) = a0;
    *(uint4*)(As + (r0 + 64) * 40 + kc0) = a1;
    *(uint4*)(Bs + r0 * 40 + kc0) = b0;
    *(uint4*)(Bs + (r0 + 64) * 40 + kc0) = b1;
    __syncthreads();
    short8 af[4], bf[4];
#pragma unroll
    for (int mt = 0; mt < 4; mt++) af[mt] = *(const short8*)(As + (wm + mt * 16 + l15) * 40 + quad * 8);
#pragma unroll
    for (int nt = 0; nt < 4; nt++) bf[nt] = *(const short8*)(Bs + (wn + nt * 16 + l15) * 40 + quad * 8);
#pragma unroll
    for (int mt = 0; mt < 4; mt++)
#pragma unroll
      for (int nt = 0; nt < 4; nt++)
        acc[mt][nt] = __builtin_amdgcn_mfma_f32_16x16x32_bf16(af[mt], bf[nt], acc[mt][nt], 0, 0, 0);
  }
#pragma unroll
  for (int mt = 0; mt < 4; mt++) {
#pragma unroll
    for (int nt = 0; nt < 4; nt++) {
      const int col = n0 + wn + nt * 16 + l15;
      const float bcol = bias[col];
#pragma unroll
      for (int r = 0; r < 4; r++) {
        const int row = m0 + wm + mt * 16 + quad * 4 + r;  // C/D: row=(lane>>4)*4+reg, col=lane&15
        out[(size_t)row * 512 + col] = acc[mt][nt][r] + bcol;
      }
    }
  }
}

// ---------------------------------------------------------------------------
// alpha/beta: one wave per row; dot(x_row, Wa) and dot(x_row, Wb), sigmoid.
// all f32.
// ---------------------------------------------------------------------------
__global__ __launch_bounds__(256) void ab_kernel(
    const float* __restrict__ x, const float* __restrict__ Wa, const float* __restrict__ ba,
    const float* __restrict__ Wb, const float* __restrict__ bb,
    float* __restrict__ alpha, float* __restrict__ beta)
{
  const int lane = threadIdx.x & 63, wave = threadIdx.x >> 6;
  const int row = blockIdx.x * 4 + wave;
  const float4 x0 = *(const float4*)(x + (size_t)row * 512 + lane * 8);
  const float4 x1 = *(const float4*)(x + (size_t)row * 512 + lane * 8 + 4);
  const float4 a0 = *(const float4*)(Wa + lane * 8);
  const float4 a1 = *(const float4*)(Wa + lane * 8 + 4);
  const float4 b0 = *(const float4*)(Wb + lane * 8);
  const float4 b1 = *(const float4*)(Wb + lane * 8 + 4);
  float da = x0.x*a0.x + x0.y*a0.y + x0.z*a0.z + x0.w*a0.w
           + x1.x*a1.x + x1.y*a1.y + x1.z*a1.z + x1.w*a1.w;
  float db = x0.x*b0.x + x0.y*b0.y + x0.z*b0.z + x0.w*b0.w
           + x1.x*b1.x + x1.y*b1.y + x1.z*b1.z + x1.w*b1.w;
#pragma unroll
  for (int m = 32; m >= 1; m >>= 1) { da += __shfl_xor(da, m, 64); db += __shfl_xor(db, m, 64); }
  if (lane == 0) {
    alpha[row] = sigm(da + ba[0]);
    beta[row]  = sigm(db + bb[0]);
  }
}

// ---------------------------------------------------------------------------
// causal depthwise conv (k=4) + SiLU (+ L2 norm for q,k). One block per (b,t).
// all f32.
// ---------------------------------------------------------------------------
__global__ __launch_bounds__(256) void conv_act(
    const float* __restrict__ lq, const float* __restrict__ lk, const float* __restrict__ lv,
    const float* __restrict__ cwq, const float* __restrict__ cbq,
    const float* __restrict__ cwk, const float* __restrict__ cbk,
    const float* __restrict__ cwv, const float* __restrict__ cbv,
    float* __restrict__ oq, float* __restrict__ ok, float* __restrict__ ov)
{
  __shared__ float red[4];
  const int row = blockIdx.x;
  const int z = blockIdx.y;                 // 0:q 1:k 2:v
  const int b = row / S_, t = row - b * S_;
  const float* lin = (z == 0) ? lq : (z == 1) ? lk : lv;
  const float* cw = (z == 0) ? cwq : (z == 1) ? cwk : cwv;
  const float* cb = (z == 0) ? cbq : (z == 1) ? cbk : cbv;
  float* outp = (z == 0) ? oq : (z == 1) ? ok : ov;
  const int tid = threadIdx.x;
  float s[2]; float ssq = 0.f;
#pragma unroll
  for (int e = 0; e < 2; e++) {
    const int ch = tid + e * 256;
    float acc = cb[ch];
#pragma unroll
    for (int tau = 0; tau < 4; tau++) {
      const int tt = t - 3 + tau;
      if (tt >= 0) acc = fmaf(lin[(size_t)(b * S_ + tt) * D_ + ch], cw[ch * 4 + tau], acc);
    }
    const float sv = acc * sigm(acc);       // silu
    s[e] = sv; ssq = fmaf(sv, sv, ssq);
  }
  if (z < 2) {                               // l2 norm over d
    float v = ssq;
#pragma unroll
    for (int m = 32; m >= 1; m >>= 1) v += __shfl_xor(v, m, 64);
    if ((tid & 63) == 0) red[tid >> 6] = v;
    __syncthreads();
    const float tot = red[0] + red[1] + red[2] + red[3];
    const float scale = 1.0f / fmaxf(sqrtf(tot), 1e-12f);
    s[0] *= scale; s[1] *= scale;
  }
  outp[(size_t)row * D_ + tid] = s[0];
  outp[(size_t)row * D_ + tid + 256] = s[1];
}

// ---------------------------------------------------------------------------
// gated delta scan. Each 32-lane half-wave owns ONE state row (16 f32 cols/lane).
// 512 thr = 16 rows. grid: (D/16=32 row-groups, B=8). k/q staged 8 steps/chunk
// (LDS ~33 KB, under the safe 64 KB/WG bound).
// ---------------------------------------------------------------------------
#define TC_ 8
__global__ __launch_bounds__(512) void scan_kernel(
    const float* __restrict__ qa, const float* __restrict__ ka, const float* __restrict__ va,
    const float* __restrict__ alpha, const float* __restrict__ beta,
    float* __restrict__ gdn)
{
  __shared__ float k_s[TC_ * 512];
  __shared__ float q_s[TC_ * 512];
  __shared__ float v_s[TC_ * 16];
  __shared__ float a_s[TC_];
  __shared__ float b_s[TC_];
  __shared__ float o_s[TC_ * 16];
  const int b = blockIdx.y;
  const int i0 = blockIdx.x * 16;
  const int tid = threadIdx.x;
  const int lane = tid & 63, wave = tid >> 6;
  const int p = lane & 31;                       // position within 32-lane group
  const int row_local = wave * 2 + (lane >> 5);  // 0..15
  const size_t baseB = (size_t)b * S_ * D_;
  float S[16];
#pragma unroll
  for (int j = 0; j < 16; j++) S[j] = 0.f;

  for (int t0 = 0; t0 < S_; t0 += TC_) {
    __syncthreads();
    {
      const float* kg = ka + baseB + (size_t)t0 * D_;
      const float* qg = qa + baseB + (size_t)t0 * D_;
#pragma unroll
      for (int it = 0; it < 2; it++) {
        const int vi = (tid + it * 512) * 4;
        *(float4*)&k_s[vi] = *(const float4*)(kg + vi);
        *(float4*)&q_s[vi] = *(const float4*)(qg + vi);
      }
      if (tid < TC_ * 16) {
        const int tt = tid >> 4, ii = tid & 15;
        v_s[tid] = va[baseB + (size_t)(t0 + tt) * D_ + i0 + ii];
      }
      if (tid >= 256 && tid < 256 + TC_) a_s[tid - 256] = alpha[b * S_ + t0 + tid - 256];
      if (tid >= 320 && tid < 320 + TC_) b_s[tid - 320] = beta[b * S_ + t0 + tid - 320];
    }
    __syncthreads();
#pragma unroll 1
    for (int t = 0; t < TC_; t++) {
      const float* kt = &k_s[t * 512 + p * 16];
      const float* qt = &q_s[t * 512 + p * 16];
      float kf[16], qf[16];
      *(float4*)&kf[0]  = *(const float4*)(kt);
      *(float4*)&kf[4]  = *(const float4*)(kt + 4);
      *(float4*)&kf[8]  = *(const float4*)(kt + 8);
      *(float4*)&kf[12] = *(const float4*)(kt + 12);
      *(float4*)&qf[0]  = *(const float4*)(qt);
      *(float4*)&qf[4]  = *(const float4*)(qt + 4);
      *(float4*)&qf[8]  = *(const float4*)(qt + 8);
      *(float4*)&qf[12] = *(const float4*)(qt + 12);
      float d = 0.f;
#pragma unroll
      for (int j = 0; j < 16; j++) d = fmaf(S[j], kf[j], d);
      d += __shfl_xor(d, 1);  d += __shfl_xor(d, 2);  d += __shfl_xor(d, 4);
      d += __shfl_xor(d, 8);  d += __shfl_xor(d, 16);
      const float a = a_s[t], bb = b_s[t];
      const float vv = v_s[t * 16 + row_local];
      const float c = bb * (vv - a * d);       // S_ij <- a*S_ij + c*k_j
      float o = 0.f;
#pragma unroll
      for (int j = 0; j < 16; j++) { S[j] = fmaf(a, S[j], c * kf[j]); o = fmaf(S[j], qf[j], o); }
      o += __shfl_xor(o, 1);  o += __shfl_xor(o, 2);  o += __shfl_xor(o, 4);
      o += __shfl_xor(o, 8);  o += __shfl_xor(o, 16);
      if (p == 0) o_s[t * 16 + row_local] = o;
    }
    __syncthreads();
    if (tid < TC_ * 16) {
      const int tt = tid >> 4, ii = tid & 15;
      gdn[baseB + (size_t)(t0 + tt) * D_ + i0 + ii] = o_s[tid];
    }
  }
}

// ---------------------------------------------------------------------------
// zero-centered rmsnorm * norm_w * silu(gate) -> bf16 h (for the final GEMM)
// ---------------------------------------------------------------------------
__global__ __launch_bounds__(256) void norm_gate(
    const float* __restrict__ gdn, const float* __restrict__ lg,
    const float* __restrict__ nw, u16* __restrict__ h)
{
  __shared__ float red[8];
  const int row = blockIdx.x, tid = threadIdx.x;
  const size_t base = (size_t)row * D_;
  const float g0 = gdn[base + tid], g1 = gdn[base + tid + 256];
  float sm = g0 + g1;
#pragma unroll
  for (int m = 32; m >= 1; m >>= 1) sm += __shfl_xor(sm, m, 64);
  if ((tid & 63) == 0) red[tid >> 6] = sm;
  __syncthreads();
  const float mean = (red[0] + red[1] + red[2] + red[3]) * (1.0f / 512.0f);
  const float x0 = g0 - mean, x1 = g1 - mean;
  float sq = x0 * x0 + x1 * x1;
#pragma unroll
  for (int m = 32; m >= 1; m >>= 1) sq += __shfl_xor(sq, m, 64);
  if ((tid & 63) == 0) red[4 + (tid >> 6)] = sq;
  __syncthreads();
  const float var = (red[4] + red[5] + red[6] + red[7]) * (1.0f / 512.0f);
  const float rst = rsqrtf(var + 1e-5f);
  const float gl0 = lg[base + tid];
  h[base + tid] = f2bf(x0 * rst * nw[tid] * (gl0 * sigm(gl0)));
  const float gl1 = lg[base + tid + 256];
  h[base + tid + 256] = f2bf(x1 * rst * nw[tid + 256] * (gl1 * sigm(gl1)));
}

// ---------------------------------------------------------------------------
extern "C" void kernel_launch(void* const* d_in, const int* in_sizes, int n_in,
                              void* d_out, int out_size, void* d_ws, size_t ws_size,
                              hipStream_t stream)
{
  const float* x   = (const float*)d_in[0];
  const float* Wq  = (const float*)d_in[1];
  const float* bq  = (const float*)d_in[2];
  const float* Wk  = (const float*)d_in[3];
  const float* bk  = (const float*)d_in[4];
  const float* Wv  = (const float*)d_in[5];
  const float* bv  = (const float*)d_in[6];
  const float* Wa  = (const float*)d_in[7];
  const float* ba  = (const float*)d_in[8];
  const float* Wb  = (const float*)d_in[9];
  const float* bb  = (const float*)d_in[10];
  const float* cwq = (const float*)d_in[11];
  const float* cbq = (const float*)d_in[12];
  const float* cwk = (const float*)d_in[13];
  const float* cbk = (const float*)d_in[14];
  const float* cwv = (const float*)d_in[15];
  const float* cbv = (const float*)d_in[16];
  const float* nw  = (const float*)d_in[17];
  const float* Wg  = (const float*)d_in[18];
  const float* bg  = (const float*)d_in[19];
  const float* Wo  = (const float*)d_in[20];
  const float* bo  = (const float*)d_in[21];

  float* ws    = (float*)d_ws;
  float* lin_q = ws;               // f32, reused as gdn after conv
  float* lin_k = ws + ND_;
  float* lin_v = ws + 2 * ND_;     // f32, reused as h(bf16) after conv
  float* lin_g = ws + 3 * ND_;
  float* qb    = ws + 4 * ND_;
  float* kb    = ws + 5 * ND_;
  float* vb    = ws + 6 * ND_;
  float* alpha = ws + 7 * ND_;
  float* beta  = alpha + N_;
  u16*   xb    = (u16*)(beta + N_);               // ND_ bf16
  u16*   wq_b  = xb + ND_;                        // 5 x 512*512 bf16
  u16*   wk_b  = wq_b + 512 * 512;
  u16*   wv_b  = wk_b + 512 * 512;
  u16*   wg_b  = wv_b + 512 * 512;
  u16*   wo_b  = wg_b + 512 * 512;
  float* gdn   = lin_q;
  u16*   h     = (u16*)lin_v;

  const int NW = 512 * 512;
  cvt_bf16<<<(int)(ND_ / 1024), 256, 0, stream>>>(x, xb, (int)ND_);
  cvt_bf16<<<NW / 1024, 256, 0, stream>>>(Wq, wq_b, NW);
  cvt_bf16<<<NW / 1024, 256, 0, stream>>>(Wk, wk_b, NW);
  cvt_bf16<<<NW / 1024, 256, 0, stream>>>(Wv, wv_b, NW);
  cvt_bf16<<<NW / 1024, 256, 0, stream>>>(Wg, wg_b, NW);
  cvt_bf16<<<NW / 1024, 256, 0, stream>>>(Wo, wo_b, NW);

  dim3 gg(128, 4);
  gemm_bt<<<gg, 256, 0, stream>>>(xb, wq_b, bq, lin_q);
  gemm_bt<<<gg, 256, 0, stream>>>(xb, wk_b, bk, lin_k);
  gemm_bt<<<gg, 256, 0, stream>>>(xb, wv_b, bv, lin_v);
  gemm_bt<<<gg, 256, 0, stream>>>(xb, wg_b, bg, lin_g);
  ab_kernel<<<N_ / 4, 256, 0, stream>>>(x, Wa, ba, Wb, bb, alpha, beta);
  conv_act<<<dim3(N_, 3), 256, 0, stream>>>(lin_q, lin_k, lin_v,
                                            cwq, cbq, cwk, cbk, cwv, cbv, qb, kb, vb);
  scan_kernel<<<dim3(D_ / 16, B_), 512, 0, stream>>>(qb, kb, vb, alpha, beta, gdn);
  norm_gate<<<N_, 256, 0, stream>>>(gdn, lin_g, nw, h);
  gemm_bt<<<gg, 256, 0, stream>>>(h, wo_b, bo, (float*)d_out);
}

// Round 3
// 1520.014 us; speedup vs baseline: 1.3661x; 1.3661x over previous
//
#include <hip/hip_runtime.h>
#include <math.h>

typedef unsigned short u16;
typedef unsigned int u32;
typedef short short8 __attribute__((ext_vector_type(8)));
typedef float f32x4 __attribute__((ext_vector_type(4)));

#define B_ 8
#define S_ 2048
#define D_ 512
#define N_ (B_ * S_)
#define ND_ ((size_t)N_ * D_)

__device__ __forceinline__ u16 f2bf(float f) {
  union { float f; u32 i; } v; v.f = f;
  u32 i = v.i;
  i += 0x7FFFu + ((i >> 16) & 1u);   // round-to-nearest-even
  return (u16)(i >> 16);
}
__device__ __forceinline__ float sigm(float x) { return 1.0f / (1.0f + expf(-x)); }

// 64-lane sum via DPP (VALU pipe, zero DS ops); result uniform via readlane(63).
__device__ __forceinline__ float dpp_sum64(float x) {
  float s = x;
  s += __hip_ds_bpermutef ? 0.f : 0.f;  // no-op; keep compiler happy about unused warnings
  s = x;
  s += __int_as_float(__builtin_amdgcn_update_dpp(0, __float_as_int(s), 0x111, 0xf, 0xf, true)); // row_shr:1
  s += __int_as_float(__builtin_amdgcn_update_dpp(0, __float_as_int(s), 0x112, 0xf, 0xf, true)); // row_shr:2
  s += __int_as_float(__builtin_amdgcn_update_dpp(0, __float_as_int(s), 0x114, 0xf, 0xf, true)); // row_shr:4
  s += __int_as_float(__builtin_amdgcn_update_dpp(0, __float_as_int(s), 0x118, 0xf, 0xf, true)); // row_shr:8
  s += __int_as_float(__builtin_amdgcn_update_dpp(0, __float_as_int(s), 0x142, 0xf, 0xf, true)); // row_bcast:15
  s += __int_as_float(__builtin_amdgcn_update_dpp(0, __float_as_int(s), 0x143, 0xf, 0xf, true)); // row_bcast:31
  return __int_as_float(__builtin_amdgcn_readlane(__float_as_int(s), 63));
}

// ---------------------------------------------------------------------------
// f32 -> bf16 conversion (x and weight matrices), n % 4 == 0
// ---------------------------------------------------------------------------
__global__ __launch_bounds__(256) void cvt_bf16(const float* __restrict__ s,
                                                u16* __restrict__ d, int n)
{
  const int i = (blockIdx.x * 256 + threadIdx.x) * 4;
  if (i < n) {
    const float4 v = *(const float4*)(s + i);
    ushort4 o;
    o.x = f2bf(v.x); o.y = f2bf(v.y); o.z = f2bf(v.z); o.w = f2bf(v.w);
    *(ushort4*)(d + i) = o;
  }
}

// ---------------------------------------------------------------------------
// GEMM: out[m,n] = sum_k A[m,k]*W[n,k] + bias[n]; bf16 in, f32 out.
// ---------------------------------------------------------------------------
__global__ __launch_bounds__(256) void gemm_bt(
    const u16* __restrict__ A, const u16* __restrict__ W,
    const float* __restrict__ bias, float* __restrict__ out)
{
  __shared__ u16 As[128 * 40];
  __shared__ u16 Bs[128 * 40];
  const int tid = threadIdx.x;
  const int lane = tid & 63, wave = tid >> 6;
  const int wm = (wave >> 1) * 64, wn = (wave & 1) * 64;
  const int l15 = lane & 15, quad = lane >> 4;
  const int m0 = blockIdx.x * 128, n0 = blockIdx.y * 128;
  const int r0 = tid >> 2;
  const int kc0 = (tid & 3) * 8;

  f32x4 acc[4][4];
#pragma unroll
  for (int i = 0; i < 4; i++)
#pragma unroll
    for (int j = 0; j < 4; j++) acc[i][j] = (f32x4){0.f, 0.f, 0.f, 0.f};

  for (int k0 = 0; k0 < 512; k0 += 32) {
    uint4 a0 = *(const uint4*)(A + (size_t)(m0 + r0) * 512 + k0 + kc0);
    uint4 a1 = *(const uint4*)(A + (size_t)(m0 + r0 + 64) * 512 + k0 + kc0);
    uint4 b0 = *(const uint4*)(W + (size_t)(n0 + r0) * 512 + k0 + kc0);
    uint4 b1 = *(const uint4*)(W + (size_t)(n0 + r0 + 64) * 512 + k0 + kc0);
    __syncthreads();
    *(uint4*)(As + r0 * 40 + kc0) = a0;
    *(uint4*)(As + (r0 + 64) * 40 + kc0) = a1;
    *(uint4*)(Bs + r0 * 40 + kc0) = b0;
    *(uint4*)(Bs + (r0 + 64) * 40 + kc0) = b1;
    __syncthreads();
    short8 af[4], bf[4];
#pragma unroll
    for (int mt = 0; mt < 4; mt++) af[mt] = *(const short8*)(As + (wm + mt * 16 + l15) * 40 + quad * 8);
#pragma unroll
    for (int nt = 0; nt < 4; nt++) bf[nt] = *(const short8*)(Bs + (wn + nt * 16 + l15) * 40 + quad * 8);
#pragma unroll
    for (int mt = 0; mt < 4; mt++)
#pragma unroll
      for (int nt = 0; nt < 4; nt++)
        acc[mt][nt] = __builtin_amdgcn_mfma_f32_16x16x32_bf16(af[mt], bf[nt], acc[mt][nt], 0, 0, 0);
  }
#pragma unroll
  for (int mt = 0; mt < 4; mt++) {
#pragma unroll
    for (int nt = 0; nt < 4; nt++) {
      const int col = n0 + wn + nt * 16 + l15;
      const float bcol = bias[col];
#pragma unroll
      for (int r = 0; r < 4; r++) {
        const int row = m0 + wm + mt * 16 + quad * 4 + r;
        out[(size_t)row * 512 + col] = acc[mt][nt][r] + bcol;
      }
    }
  }
}

// ---------------------------------------------------------------------------
// alpha/beta
// ---------------------------------------------------------------------------
__global__ __launch_bounds__(256) void ab_kernel(
    const float* __restrict__ x, const float* __restrict__ Wa, const float* __restrict__ ba,
    const float* __restrict__ Wb, const float* __restrict__ bb,
    float* __restrict__ alpha, float* __restrict__ beta)
{
  const int lane = threadIdx.x & 63, wave = threadIdx.x >> 6;
  const int row = blockIdx.x * 4 + wave;
  const float4 x0 = *(const float4*)(x + (size_t)row * 512 + lane * 8);
  const float4 x1 = *(const float4*)(x + (size_t)row * 512 + lane * 8 + 4);
  const float4 a0 = *(const float4*)(Wa + lane * 8);
  const float4 a1 = *(const float4*)(Wa + lane * 8 + 4);
  const float4 b0 = *(const float4*)(Wb + lane * 8);
  const float4 b1 = *(const float4*)(Wb + lane * 8 + 4);
  float da = x0.x*a0.x + x0.y*a0.y + x0.z*a0.z + x0.w*a0.w
           + x1.x*a1.x + x1.y*a1.y + x1.z*a1.z + x1.w*a1.w;
  float db = x0.x*b0.x + x0.y*b0.y + x0.z*b0.z + x0.w*b0.w
           + x1.x*b1.x + x1.y*b1.y + x1.z*b1.z + x1.w*b1.w;
#pragma unroll
  for (int m = 32; m >= 1; m >>= 1) { da += __shfl_xor(da, m, 64); db += __shfl_xor(db, m, 64); }
  if (lane == 0) {
    alpha[row] = sigm(da + ba[0]);
    beta[row]  = sigm(db + bb[0]);
  }
}

// ---------------------------------------------------------------------------
// causal depthwise conv (k=4) + SiLU (+ L2 norm for q,k)
// ---------------------------------------------------------------------------
__global__ __launch_bounds__(256) void conv_act(
    const float* __restrict__ lq, const float* __restrict__ lk, const float* __restrict__ lv,
    const float* __restrict__ cwq, const float* __restrict__ cbq,
    const float* __restrict__ cwk, const float* __restrict__ cbk,
    const float* __restrict__ cwv, const float* __restrict__ cbv,
    float* __restrict__ oq, float* __restrict__ ok, float* __restrict__ ov)
{
  __shared__ float red[4];
  const int row = blockIdx.x;
  const int z = blockIdx.y;
  const int b = row / S_, t = row - b * S_;
  const float* lin = (z == 0) ? lq : (z == 1) ? lk : lv;
  const float* cw = (z == 0) ? cwq : (z == 1) ? cwk : cwv;
  const float* cb = (z == 0) ? cbq : (z == 1) ? cbk : cbv;
  float* outp = (z == 0) ? oq : (z == 1) ? ok : ov;
  const int tid = threadIdx.x;
  float s[2]; float ssq = 0.f;
#pragma unroll
  for (int e = 0; e < 2; e++) {
    const int ch = tid + e * 256;
    float acc = cb[ch];
#pragma unroll
    for (int tau = 0; tau < 4; tau++) {
      const int tt = t - 3 + tau;
      if (tt >= 0) acc = fmaf(lin[(size_t)(b * S_ + tt) * D_ + ch], cw[ch * 4 + tau], acc);
    }
    const float sv = acc * sigm(acc);
    s[e] = sv; ssq = fmaf(sv, sv, ssq);
  }
  if (z < 2) {
    float v = ssq;
#pragma unroll
    for (int m = 32; m >= 1; m >>= 1) v += __shfl_xor(v, m, 64);
    if ((tid & 63) == 0) red[tid >> 6] = v;
    __syncthreads();
    const float tot = red[0] + red[1] + red[2] + red[3];
    const float scale = 1.0f / fmaxf(sqrtf(tot), 1e-12f);
    s[0] *= scale; s[1] *= scale;
  }
  outp[(size_t)row * D_ + tid] = s[0];
  outp[(size_t)row * D_ + tid + 256] = s[1];
}

// ---------------------------------------------------------------------------
// gated delta scan, v2.
// Block = 256 thr = 4 waves; each wave owns 2 state rows; lane p owns cols
// [8p..8p+7] SHARED by both rows (k/q fragments loaded once per wave).
// LDS: lane segments padded to stride 12 -> 2-way banks (free).
// Reductions: DPP row_shr/bcast (VALU) + readlane, no ds_swizzle.
// o_t = a*(S.q) + c*(k.q), with k.q precomputed per chunk.
// grid: (512/8 row-groups, B) = (64,8) = 512 blocks.
// ---------------------------------------------------------------------------
#define TC_ 8
#define RSTRIDE_ 768   // 64 lanes * 12
__global__ __launch_bounds__(256) void scan_kernel(
    const float* __restrict__ qa, const float* __restrict__ ka, const float* __restrict__ va,
    const float* __restrict__ alpha, const float* __restrict__ beta,
    float* __restrict__ gdn)
{
  __shared__ float k_s[TC_ * RSTRIDE_];
  __shared__ float q_s[TC_ * RSTRIDE_];
  __shared__ float v_s[TC_ * 8];
  __shared__ float abk_s[TC_ * 4];   // per t: {alpha, beta, k.q, pad}
  __shared__ float o_s[TC_ * 8];
  const int b = blockIdx.y;
  const int i0 = blockIdx.x * 8;
  const int tid = threadIdx.x;
  const int lane = tid & 63, wave = tid >> 6;   // wave 0..3
  const size_t baseB = (size_t)b * S_ * D_;
  const int lbase = lane * 12;

  float S0[8], S1[8];
#pragma unroll
  for (int j = 0; j < 8; j++) { S0[j] = 0.f; S1[j] = 0.f; }

  for (int t0 = 0; t0 < S_; t0 += TC_) {
    __syncthreads();
    // ---- stage k,q (coalesced global float4 -> padded LDS) ----
    {
      const float* kg = ka + baseB + (size_t)t0 * D_;
      const float* qg = qa + baseB + (size_t)t0 * D_;
#pragma unroll
      for (int i = 0; i < 4; i++) {
        const int f = tid + i * 256;            // float4 index in [0,1024)
        const int t = f >> 7, j4 = f & 127;
        const int p = j4 >> 1, c = j4 & 1;
        const int la = t * RSTRIDE_ + p * 12 + c * 4;
        *(float4*)&k_s[la] = *(const float4*)(kg + f * 4);
        *(float4*)&q_s[la] = *(const float4*)(qg + f * 4);
      }
      if (tid < TC_ * 8) {
        const int t = tid >> 3, r = tid & 7;
        v_s[tid] = va[baseB + (size_t)(t0 + t) * D_ + i0 + r];
      }
      if (tid >= 128 && tid < 128 + TC_) abk_s[(tid - 128) * 4 + 0] = alpha[b * S_ + t0 + tid - 128];
      if (tid >= 160 && tid < 160 + TC_) abk_s[(tid - 160) * 4 + 1] = beta[b * S_ + t0 + tid - 160];
    }
    __syncthreads();
    // ---- k.q per step (waves cooperate, DPP reduce) ----
#pragma unroll
    for (int tt = wave; tt < TC_; tt += 4) {
      const float* kp = &k_s[tt * RSTRIDE_ + lbase];
      const float* qp = &q_s[tt * RSTRIDE_ + lbase];
      float kf[8], qf[8];
      *(float4*)&kf[0] = *(const float4*)kp;  *(float4*)&kf[4] = *(const float4*)(kp + 4);
      *(float4*)&qf[0] = *(const float4*)qp;  *(float4*)&qf[4] = *(const float4*)(qp + 4);
      float pk = 0.f;
#pragma unroll
      for (int j = 0; j < 8; j++) pk = fmaf(kf[j], qf[j], pk);
      const float kq = dpp_sum64(pk);
      if (lane == 0) abk_s[tt * 4 + 2] = kq;
    }
    __syncthreads();
    // ---- 8 serial steps ----
#pragma unroll
    for (int t = 0; t < TC_; t++) {
      const float* kp = &k_s[t * RSTRIDE_ + lbase];
      const float* qp = &q_s[t * RSTRIDE_ + lbase];
      float kf[8], qf[8];
      *(float4*)&kf[0] = *(const float4*)kp;  *(float4*)&kf[4] = *(const float4*)(kp + 4);
      *(float4*)&qf[0] = *(const float4*)qp;  *(float4*)&qf[4] = *(const float4*)(qp + 4);
      float d0 = 0.f, d1 = 0.f, e0 = 0.f, e1 = 0.f;
#pragma unroll
      for (int j = 0; j < 8; j++) {
        d0 = fmaf(S0[j], kf[j], d0);
        d1 = fmaf(S1[j], kf[j], d1);
        e0 = fmaf(S0[j], qf[j], e0);
        e1 = fmaf(S1[j], qf[j], e1);
      }
      const float D0 = dpp_sum64(d0), D1 = dpp_sum64(d1);
      const float E0 = dpp_sum64(e0), E1 = dpp_sum64(e1);
      const float4 abk = *(const float4*)&abk_s[t * 4];
      const float2 vv = *(const float2*)&v_s[t * 8 + 2 * wave];
      const float a = abk.x, bt = abk.y, kq = abk.z;
      const float c0 = bt * (vv.x - a * D0);
      const float c1 = bt * (vv.y - a * D1);
      const float o0 = fmaf(a, E0, c0 * kq);
      const float o1 = fmaf(a, E1, c1 * kq);
#pragma unroll
      for (int j = 0; j < 8; j++) {
        S0[j] = fmaf(a, S0[j], c0 * kf[j]);
        S1[j] = fmaf(a, S1[j], c1 * kf[j]);
      }
      if (lane == 0) {
        o_s[t * 8 + 2 * wave]     = o0;
        o_s[t * 8 + 2 * wave + 1] = o1;
      }
    }
    __syncthreads();
    if (tid < TC_ * 8) {
      const int t = tid >> 3, r = tid & 7;
      gdn[baseB + (size_t)(t0 + t) * D_ + i0 + r] = o_s[tid];
    }
  }
}

// ---------------------------------------------------------------------------
// zero-centered rmsnorm * norm_w * silu(gate) -> bf16 h
// ---------------------------------------------------------------------------
__global__ __launch_bounds__(256) void norm_gate(
    const float* __restrict__ gdn, const float* __restrict__ lg,
    const float* __restrict__ nw, u16* __restrict__ h)
{
  __shared__ float red[8];
  const int row = blockIdx.x, tid = threadIdx.x;
  const size_t base = (size_t)row * D_;
  const float g0 = gdn[base + tid], g1 = gdn[base + tid + 256];
  float sm = g0 + g1;
#pragma unroll
  for (int m = 32; m >= 1; m >>= 1) sm += __shfl_xor(sm, m, 64);
  if ((tid & 63) == 0) red[tid >> 6] = sm;
  __syncthreads();
  const float mean = (red[0] + red[1] + red[2] + red[3]) * (1.0f / 512.0f);
  const float x0 = g0 - mean, x1 = g1 - mean;
  float sq = x0 * x0 + x1 * x1;
#pragma unroll
  for (int m = 32; m >= 1; m >>= 1) sq += __shfl_xor(sq, m, 64);
  if ((tid & 63) == 0) red[4 + (tid >> 6)] = sq;
  __syncthreads();
  const float var = (red[4] + red[5] + red[6] + red[7]) * (1.0f / 512.0f);
  const float rst = rsqrtf(var + 1e-5f);
  const float gl0 = lg[base + tid];
  h[base + tid] = f2bf(x0 * rst * nw[tid] * (gl0 * sigm(gl0)));
  const float gl1 = lg[base + tid + 256];
  h[base + tid + 256] = f2bf(x1 * rst * nw[tid + 256] * (gl1 * sigm(gl1)));
}

// ---------------------------------------------------------------------------
extern "C" void kernel_launch(void* const* d_in, const int* in_sizes, int n_in,
                              void* d_out, int out_size, void* d_ws, size_t ws_size,
                              hipStream_t stream)
{
  const float* x   = (const float*)d_in[0];
  const float* Wq  = (const float*)d_in[1];
  const float* bq  = (const float*)d_in[2];
  const float* Wk  = (const float*)d_in[3];
  const float* bk  = (const float*)d_in[4];
  const float* Wv  = (const float*)d_in[5];
  const float* bv  = (const float*)d_in[6];
  const float* Wa  = (const float*)d_in[7];
  const float* ba  = (const float*)d_in[8];
  const float* Wb  = (const float*)d_in[9];
  const float* bb  = (const float*)d_in[10];
  const float* cwq = (const float*)d_in[11];
  const float* cbq = (const float*)d_in[12];
  const float* cwk = (const float*)d_in[13];
  const float* cbk = (const float*)d_in[14];
  const float* cwv = (const float*)d_in[15];
  const float* cbv = (const float*)d_in[16];
  const float* nw  = (const float*)d_in[17];
  const float* Wg  = (const float*)d_in[18];
  const float* bg  = (const float*)d_in[19];
  const float* Wo  = (const float*)d_in[20];
  const float* bo  = (const float*)d_in[21];

  float* ws    = (float*)d_ws;
  float* lin_q = ws;               // f32, reused as gdn after conv
  float* lin_k = ws + ND_;
  float* lin_v = ws + 2 * ND_;     // f32, reused as h(bf16) after conv
  float* lin_g = ws + 3 * ND_;
  float* qb    = ws + 4 * ND_;
  float* kb    = ws + 5 * ND_;
  float* vb    = ws + 6 * ND_;
  float* alpha = ws + 7 * ND_;
  float* beta  = alpha + N_;
  u16*   xb    = (u16*)(beta + N_);
  u16*   wq_b  = xb + ND_;
  u16*   wk_b  = wq_b + 512 * 512;
  u16*   wv_b  = wk_b + 512 * 512;
  u16*   wg_b  = wv_b + 512 * 512;
  u16*   wo_b  = wg_b + 512 * 512;
  float* gdn   = lin_q;
  u16*   h     = (u16*)lin_v;

  const int NW = 512 * 512;
  cvt_bf16<<<(int)(ND_ / 1024), 256, 0, stream>>>(x, xb, (int)ND_);
  cvt_bf16<<<NW / 1024, 256, 0, stream>>>(Wq, wq_b, NW);
  cvt_bf16<<<NW / 1024, 256, 0, stream>>>(Wk, wk_b, NW);
  cvt_bf16<<<NW / 1024, 256, 0, stream>>>(Wv, wv_b, NW);
  cvt_bf16<<<NW / 1024, 256, 0, stream>>>(Wg, wg_b, NW);
  cvt_bf16<<<NW / 1024, 256, 0, stream>>>(Wo, wo_b, NW);

  dim3 gg(128, 4);
  gemm_bt<<<gg, 256, 0, stream>>>(xb, wq_b, bq, lin_q);
  gemm_bt<<<gg, 256, 0, stream>>>(xb, wk_b, bk, lin_k);
  gemm_bt<<<gg, 256, 0, stream>>>(xb, wv_b, bv, lin_v);
  gemm_bt<<<gg, 256, 0, stream>>>(xb, wg_b, bg, lin_g);
  ab_kernel<<<N_ / 4, 256, 0, stream>>>(x, Wa, ba, Wb, bb, alpha, beta);
  conv_act<<<dim3(N_, 3), 256, 0, stream>>>(lin_q, lin_k, lin_v,
                                            cwq, cbq, cwk, cbk, cwv, cbv, qb, kb, vb);
  scan_kernel<<<dim3(64, 8), 256, 0, stream>>>(qb, kb, vb, alpha, beta, gdn);
  norm_gate<<<N_, 256, 0, stream>>>(gdn, lin_g, nw, h);
  gemm_bt<<<gg, 256, 0, stream>>>(h, wo_b, bo, (float*)d_out);
}

// Round 4
// 1437.943 us; speedup vs baseline: 1.4440x; 1.0571x over previous
//
#include <hip/hip_runtime.h>
#include <math.h>

typedef unsigned short u16;
typedef unsigned int u32;
typedef short short8 __attribute__((ext_vector_type(8)));
typedef float f32x4 __attribute__((ext_vector_type(4)));

#define B_ 8
#define S_ 2048
#define D_ 512
#define N_ (B_ * S_)
#define ND_ ((size_t)N_ * D_)

__device__ __forceinline__ u16 f2bf(float f) {
  union { float f; u32 i; } v; v.f = f;
  u32 i = v.i;
  i += 0x7FFFu + ((i >> 16) & 1u);   // round-to-nearest-even
  return (u16)(i >> 16);
}
__device__ __forceinline__ float sigm(float x) { return 1.0f / (1.0f + expf(-x)); }

// 64-lane sum via DPP (VALU pipe, zero DS ops); result uniform via readlane(63).
// Verified correct on HW in round 3 (identical absmax to shfl version).
__device__ __forceinline__ float dpp_sum64(float x) {
  float s = x;
  s += __int_as_float(__builtin_amdgcn_update_dpp(0, __float_as_int(s), 0x111, 0xf, 0xf, true)); // row_shr:1
  s += __int_as_float(__builtin_amdgcn_update_dpp(0, __float_as_int(s), 0x112, 0xf, 0xf, true)); // row_shr:2
  s += __int_as_float(__builtin_amdgcn_update_dpp(0, __float_as_int(s), 0x114, 0xf, 0xf, true)); // row_shr:4
  s += __int_as_float(__builtin_amdgcn_update_dpp(0, __float_as_int(s), 0x118, 0xf, 0xf, true)); // row_shr:8
  s += __int_as_float(__builtin_amdgcn_update_dpp(0, __float_as_int(s), 0x142, 0xf, 0xf, true)); // row_bcast:15
  s += __int_as_float(__builtin_amdgcn_update_dpp(0, __float_as_int(s), 0x143, 0xf, 0xf, true)); // row_bcast:31
  return __int_as_float(__builtin_amdgcn_readlane(__float_as_int(s), 63));
}

// ---------------------------------------------------------------------------
// f32 -> bf16 conversion (x and weight matrices), n % 4 == 0
// ---------------------------------------------------------------------------
__global__ __launch_bounds__(256) void cvt_bf16(const float* __restrict__ s,
                                                u16* __restrict__ d, int n)
{
  const int i = (blockIdx.x * 256 + threadIdx.x) * 4;
  if (i < n) {
    const float4 v = *(const float4*)(s + i);
    ushort4 o;
    o.x = f2bf(v.x); o.y = f2bf(v.y); o.z = f2bf(v.z); o.w = f2bf(v.w);
    *(ushort4*)(d + i) = o;
  }
}

// ---------------------------------------------------------------------------
// GEMM: out[m,n] = sum_k A[m,k]*W[n,k] + bias[n]; bf16 in, f32 out.
// ---------------------------------------------------------------------------
__global__ __launch_bounds__(256) void gemm_bt(
    const u16* __restrict__ A, const u16* __restrict__ W,
    const float* __restrict__ bias, float* __restrict__ out)
{
  __shared__ u16 As[128 * 40];
  __shared__ u16 Bs[128 * 40];
  const int tid = threadIdx.x;
  const int lane = tid & 63, wave = tid >> 6;
  const int wm = (wave >> 1) * 64, wn = (wave & 1) * 64;
  const int l15 = lane & 15, quad = lane >> 4;
  const int m0 = blockIdx.x * 128, n0 = blockIdx.y * 128;
  const int r0 = tid >> 2;
  const int kc0 = (tid & 3) * 8;

  f32x4 acc[4][4];
#pragma unroll
  for (int i = 0; i < 4; i++)
#pragma unroll
    for (int j = 0; j < 4; j++) acc[i][j] = (f32x4){0.f, 0.f, 0.f, 0.f};

  for (int k0 = 0; k0 < 512; k0 += 32) {
    uint4 a0 = *(const uint4*)(A + (size_t)(m0 + r0) * 512 + k0 + kc0);
    uint4 a1 = *(const uint4*)(A + (size_t)(m0 + r0 + 64) * 512 + k0 + kc0);
    uint4 b0 = *(const uint4*)(W + (size_t)(n0 + r0) * 512 + k0 + kc0);
    uint4 b1 = *(const uint4*)(W + (size_t)(n0 + r0 + 64) * 512 + k0 + kc0);
    __syncthreads();
    *(uint4*)(As + r0 * 40 + kc0) = a0;
    *(uint4*)(As + (r0 + 64) * 40 + kc0) = a1;
    *(uint4*)(Bs + r0 * 40 + kc0) = b0;
    *(uint4*)(Bs + (r0 + 64) * 40 + kc0) = b1;
    __syncthreads();
    short8 af[4], bf[4];
#pragma unroll
    for (int mt = 0; mt < 4; mt++) af[mt] = *(const short8*)(As + (wm + mt * 16 + l15) * 40 + quad * 8);
#pragma unroll
    for (int nt = 0; nt < 4; nt++) bf[nt] = *(const short8*)(Bs + (wn + nt * 16 + l15) * 40 + quad * 8);
#pragma unroll
    for (int mt = 0; mt < 4; mt++)
#pragma unroll
      for (int nt = 0; nt < 4; nt++)
        acc[mt][nt] = __builtin_amdgcn_mfma_f32_16x16x32_bf16(af[mt], bf[nt], acc[mt][nt], 0, 0, 0);
  }
#pragma unroll
  for (int mt = 0; mt < 4; mt++) {
#pragma unroll
    for (int nt = 0; nt < 4; nt++) {
      const int col = n0 + wn + nt * 16 + l15;
      const float bcol = bias[col];
#pragma unroll
      for (int r = 0; r < 4; r++) {
        const int row = m0 + wm + mt * 16 + quad * 4 + r;
        out[(size_t)row * 512 + col] = acc[mt][nt][r] + bcol;
      }
    }
  }
}

// ---------------------------------------------------------------------------
// alpha/beta
// ---------------------------------------------------------------------------
__global__ __launch_bounds__(256) void ab_kernel(
    const float* __restrict__ x, const float* __restrict__ Wa, const float* __restrict__ ba,
    const float* __restrict__ Wb, const float* __restrict__ bb,
    float* __restrict__ alpha, float* __restrict__ beta)
{
  const int lane = threadIdx.x & 63, wave = threadIdx.x >> 6;
  const int row = blockIdx.x * 4 + wave;
  const float4 x0 = *(const float4*)(x + (size_t)row * 512 + lane * 8);
  const float4 x1 = *(const float4*)(x + (size_t)row * 512 + lane * 8 + 4);
  const float4 a0 = *(const float4*)(Wa + lane * 8);
  const float4 a1 = *(const float4*)(Wa + lane * 8 + 4);
  const float4 b0 = *(const float4*)(Wb + lane * 8);
  const float4 b1 = *(const float4*)(Wb + lane * 8 + 4);
  float da = x0.x*a0.x + x0.y*a0.y + x0.z*a0.z + x0.w*a0.w
           + x1.x*a1.x + x1.y*a1.y + x1.z*a1.z + x1.w*a1.w;
  float db = x0.x*b0.x + x0.y*b0.y + x0.z*b0.z + x0.w*b0.w
           + x1.x*b1.x + x1.y*b1.y + x1.z*b1.z + x1.w*b1.w;
#pragma unroll
  for (int m = 32; m >= 1; m >>= 1) { da += __shfl_xor(da, m, 64); db += __shfl_xor(db, m, 64); }
  if (lane == 0) {
    alpha[row] = sigm(da + ba[0]);
    beta[row]  = sigm(db + bb[0]);
  }
}

// ---------------------------------------------------------------------------
// causal depthwise conv (k=4) + SiLU (+ L2 norm for q,k)
// ---------------------------------------------------------------------------
__global__ __launch_bounds__(256) void conv_act(
    const float* __restrict__ lq, const float* __restrict__ lk, const float* __restrict__ lv,
    const float* __restrict__ cwq, const float* __restrict__ cbq,
    const float* __restrict__ cwk, const float* __restrict__ cbk,
    const float* __restrict__ cwv, const float* __restrict__ cbv,
    float* __restrict__ oq, float* __restrict__ ok, float* __restrict__ ov)
{
  __shared__ float red[4];
  const int row = blockIdx.x;
  const int z = blockIdx.y;
  const int b = row / S_, t = row - b * S_;
  const float* lin = (z == 0) ? lq : (z == 1) ? lk : lv;
  const float* cw = (z == 0) ? cwq : (z == 1) ? cwk : cwv;
  const float* cb = (z == 0) ? cbq : (z == 1) ? cbk : cbv;
  float* outp = (z == 0) ? oq : (z == 1) ? ok : ov;
  const int tid = threadIdx.x;
  float s[2]; float ssq = 0.f;
#pragma unroll
  for (int e = 0; e < 2; e++) {
    const int ch = tid + e * 256;
    float acc = cb[ch];
#pragma unroll
    for (int tau = 0; tau < 4; tau++) {
      const int tt = t - 3 + tau;
      if (tt >= 0) acc = fmaf(lin[(size_t)(b * S_ + tt) * D_ + ch], cw[ch * 4 + tau], acc);
    }
    const float sv = acc * sigm(acc);
    s[e] = sv; ssq = fmaf(sv, sv, ssq);
  }
  if (z < 2) {
    float v = ssq;
#pragma unroll
    for (int m = 32; m >= 1; m >>= 1) v += __shfl_xor(v, m, 64);
    if ((tid & 63) == 0) red[tid >> 6] = v;
    __syncthreads();
    const float tot = red[0] + red[1] + red[2] + red[3];
    const float scale = 1.0f / fmaxf(sqrtf(tot), 1e-12f);
    s[0] *= scale; s[1] *= scale;
  }
  outp[(size_t)row * D_ + tid] = s[0];
  outp[(size_t)row * D_ + tid + 256] = s[1];
}

// ---------------------------------------------------------------------------
// kq precompute: kq[row] = dot(k[row], q[row]); one wave per row.
// ---------------------------------------------------------------------------
__global__ __launch_bounds__(512) void kq_kernel(
    const float* __restrict__ qa, const float* __restrict__ ka, float* __restrict__ kqd)
{
  const int lane = threadIdx.x & 63, wave = threadIdx.x >> 6;
  const int row = blockIdx.x * 8 + wave;
  const size_t base = (size_t)row * D_ + lane * 8;
  const float4 k0 = *(const float4*)(ka + base);
  const float4 k1 = *(const float4*)(ka + base + 4);
  const float4 q0 = *(const float4*)(qa + base);
  const float4 q1 = *(const float4*)(qa + base + 4);
  float d = k0.x*q0.x + k0.y*q0.y + k0.z*q0.z + k0.w*q0.w
          + k1.x*q1.x + k1.y*q1.y + k1.z*q1.z + k1.w*q1.w;
  d = dpp_sum64(d);
  if (lane == 0) kqd[row] = d;
}

// ---------------------------------------------------------------------------
// gated delta scan, v3.
// One wave per state row (4096 waves = 4/SIMD). Lane p owns cols 8p..8p+7.
// No LDS, no barriers. k/q double-buffered from global (dwordx4, coalesced).
// Scaled state: S = gamma * Sh; update is 1 FMA/elem: Sh += (c/gamma)*k.
// gamma folded into Sh every TC_ steps (worst-case gamma ~2.6e-6, f32-safe).
// alpha/beta/kq/v are wave-uniform scalar loads.
// ---------------------------------------------------------------------------
#define TC_ 8
__global__ __launch_bounds__(512) void scan_kernel(
    const float* __restrict__ qa, const float* __restrict__ ka, const float* __restrict__ va,
    const float* __restrict__ alpha, const float* __restrict__ beta,
    const float* __restrict__ kqd, float* __restrict__ gdn)
{
  const int b = blockIdx.y;
  const int lane = threadIdx.x & 63;
  const int wave = threadIdx.x >> 6;
  const int row = __builtin_amdgcn_readfirstlane(blockIdx.x * 8 + wave);
  const size_t baseB = (size_t)b * S_ * D_;
  const float* kp = ka + baseB + lane * 8;
  const float* qp = qa + baseB + lane * 8;
  const float* vp = va + baseB + row;        // SGPR base -> s_load per step
  const float* ap = alpha + b * S_;
  const float* bp = beta + b * S_;
  const float* kqp = kqd + b * S_;
  float* gp = gdn + baseB + row;

  float Sh[8];
#pragma unroll
  for (int j = 0; j < 8; j++) Sh[j] = 0.f;
  float gam = 1.f;

  float4 kb_[2][2], qb_[2][2];
  kb_[0][0] = *(const float4*)(kp);
  kb_[0][1] = *(const float4*)(kp + 4);
  qb_[0][0] = *(const float4*)(qp);
  qb_[0][1] = *(const float4*)(qp + 4);

  for (int tc = 0; tc < S_ / TC_; tc++) {
#pragma unroll
    for (int tt = 0; tt < TC_; tt++) {
      const int t = tc * TC_ + tt;
      const int cur = tt & 1, nxt = cur ^ 1;
      // prefetch t+1 (last iter reads 1 row past this batch's k/q -- still
      // inside d_ws [kb->vb, qb->kb], value unused for correctness of b)
      const float* kpn = kp + (size_t)(t + 1) * D_;
      const float* qpn = qp + (size_t)(t + 1) * D_;
      kb_[nxt][0] = *(const float4*)(kpn);
      kb_[nxt][1] = *(const float4*)(kpn + 4);
      qb_[nxt][0] = *(const float4*)(qpn);
      qb_[nxt][1] = *(const float4*)(qpn + 4);
      const float4 kA = kb_[cur][0], kB = kb_[cur][1];
      const float4 qA = qb_[cur][0], qB = qb_[cur][1];
      float d = 0.f, e = 0.f;
      d = fmaf(Sh[0], kA.x, d); e = fmaf(Sh[0], qA.x, e);
      d = fmaf(Sh[1], kA.y, d); e = fmaf(Sh[1], qA.y, e);
      d = fmaf(Sh[2], kA.z, d); e = fmaf(Sh[2], qA.z, e);
      d = fmaf(Sh[3], kA.w, d); e = fmaf(Sh[3], qA.w, e);
      d = fmaf(Sh[4], kB.x, d); e = fmaf(Sh[4], qB.x, e);
      d = fmaf(Sh[5], kB.y, d); e = fmaf(Sh[5], qB.y, e);
      d = fmaf(Sh[6], kB.z, d); e = fmaf(Sh[6], qB.z, e);
      d = fmaf(Sh[7], kB.w, d); e = fmaf(Sh[7], qB.w, e);
      const float Dh = dpp_sum64(d);
      const float Eh = dpp_sum64(e);
      const float al = ap[t], be = bp[t], kq = kqp[t];
      const float vv = vp[(size_t)t * D_];
      const float gn = gam * al;                         // gamma_t
      const float c  = fmaf(-be * gn, Dh, be * vv);      // beta*(v - alpha*S.k)
      const float o  = fmaf(gn, Eh, c * kq);             // alpha*S.q + c*(k.q)
      const float cg = c * __builtin_amdgcn_rcpf(gn);
      Sh[0] = fmaf(cg, kA.x, Sh[0]);
      Sh[1] = fmaf(cg, kA.y, Sh[1]);
      Sh[2] = fmaf(cg, kA.z, Sh[2]);
      Sh[3] = fmaf(cg, kA.w, Sh[3]);
      Sh[4] = fmaf(cg, kB.x, Sh[4]);
      Sh[5] = fmaf(cg, kB.y, Sh[5]);
      Sh[6] = fmaf(cg, kB.z, Sh[6]);
      Sh[7] = fmaf(cg, kB.w, Sh[7]);
      gam = gn;
      if (lane == 0) gp[(size_t)t * D_] = o;
    }
    // fold gamma back into the state to avoid underflow
#pragma unroll
    for (int j = 0; j < 8; j++) Sh[j] *= gam;
    gam = 1.f;
  }
}

// ---------------------------------------------------------------------------
// zero-centered rmsnorm * norm_w * silu(gate) -> bf16 h
// ---------------------------------------------------------------------------
__global__ __launch_bounds__(256) void norm_gate(
    const float* __restrict__ gdn, const float* __restrict__ lg,
    const float* __restrict__ nw, u16* __restrict__ h)
{
  __shared__ float red[8];
  const int row = blockIdx.x, tid = threadIdx.x;
  const size_t base = (size_t)row * D_;
  const float g0 = gdn[base + tid], g1 = gdn[base + tid + 256];
  float sm = g0 + g1;
#pragma unroll
  for (int m = 32; m >= 1; m >>= 1) sm += __shfl_xor(sm, m, 64);
  if ((tid & 63) == 0) red[tid >> 6] = sm;
  __syncthreads();
  const float mean = (red[0] + red[1] + red[2] + red[3]) * (1.0f / 512.0f);
  const float x0 = g0 - mean, x1 = g1 - mean;
  float sq = x0 * x0 + x1 * x1;
#pragma unroll
  for (int m = 32; m >= 1; m >>= 1) sq += __shfl_xor(sq, m, 64);
  if ((tid & 63) == 0) red[4 + (tid >> 6)] = sq;
  __syncthreads();
  const float var = (red[4] + red[5] + red[6] + red[7]) * (1.0f / 512.0f);
  const float rst = rsqrtf(var + 1e-5f);
  const float gl0 = lg[base + tid];
  h[base + tid] = f2bf(x0 * rst * nw[tid] * (gl0 * sigm(gl0)));
  const float gl1 = lg[base + tid + 256];
  h[base + tid + 256] = f2bf(x1 * rst * nw[tid + 256] * (gl1 * sigm(gl1)));
}

// ---------------------------------------------------------------------------
extern "C" void kernel_launch(void* const* d_in, const int* in_sizes, int n_in,
                              void* d_out, int out_size, void* d_ws, size_t ws_size,
                              hipStream_t stream)
{
  const float* x   = (const float*)d_in[0];
  const float* Wq  = (const float*)d_in[1];
  const float* bq  = (const float*)d_in[2];
  const float* Wk  = (const float*)d_in[3];
  const float* bk  = (const float*)d_in[4];
  const float* Wv  = (const float*)d_in[5];
  const float* bv  = (const float*)d_in[6];
  const float* Wa  = (const float*)d_in[7];
  const float* ba  = (const float*)d_in[8];
  const float* Wb  = (const float*)d_in[9];
  const float* bb  = (const float*)d_in[10];
  const float* cwq = (const float*)d_in[11];
  const float* cbq = (const float*)d_in[12];
  const float* cwk = (const float*)d_in[13];
  const float* cbk = (const float*)d_in[14];
  const float* cwv = (const float*)d_in[15];
  const float* cbv = (const float*)d_in[16];
  const float* nw  = (const float*)d_in[17];
  const float* Wg  = (const float*)d_in[18];
  const float* bg  = (const float*)d_in[19];
  const float* Wo  = (const float*)d_in[20];
  const float* bo  = (const float*)d_in[21];

  float* ws    = (float*)d_ws;
  float* lin_q = ws;               // f32, reused as gdn after conv
  float* lin_k = ws + ND_;         // dead after conv -> reused for kqd
  float* lin_v = ws + 2 * ND_;     // f32, reused as h(bf16) after conv
  float* lin_g = ws + 3 * ND_;
  float* qb    = ws + 4 * ND_;
  float* kb    = ws + 5 * ND_;
  float* vb    = ws + 6 * ND_;
  float* alpha = ws + 7 * ND_;
  float* beta  = alpha + N_;
  u16*   xb    = (u16*)(beta + N_);
  u16*   wq_b  = xb + ND_;
  u16*   wk_b  = wq_b + 512 * 512;
  u16*   wv_b  = wk_b + 512 * 512;
  u16*   wg_b  = wv_b + 512 * 512;
  u16*   wo_b  = wg_b + 512 * 512;
  float* gdn   = lin_q;
  float* kqd   = lin_k;            // N_ floats, reuses dead lin_k
  u16*   h     = (u16*)lin_v;

  const int NW = 512 * 512;
  cvt_bf16<<<(int)(ND_ / 1024), 256, 0, stream>>>(x, xb, (int)ND_);
  cvt_bf16<<<NW / 1024, 256, 0, stream>>>(Wq, wq_b, NW);
  cvt_bf16<<<NW / 1024, 256, 0, stream>>>(Wk, wk_b, NW);
  cvt_bf16<<<NW / 1024, 256, 0, stream>>>(Wv, wv_b, NW);
  cvt_bf16<<<NW / 1024, 256, 0, stream>>>(Wg, wg_b, NW);
  cvt_bf16<<<NW / 1024, 256, 0, stream>>>(Wo, wo_b, NW);

  dim3 gg(128, 4);
  gemm_bt<<<gg, 256, 0, stream>>>(xb, wq_b, bq, lin_q);
  gemm_bt<<<gg, 256, 0, stream>>>(xb, wk_b, bk, lin_k);
  gemm_bt<<<gg, 256, 0, stream>>>(xb, wv_b, bv, lin_v);
  gemm_bt<<<gg, 256, 0, stream>>>(xb, wg_b, bg, lin_g);
  ab_kernel<<<N_ / 4, 256, 0, stream>>>(x, Wa, ba, Wb, bb, alpha, beta);
  conv_act<<<dim3(N_, 3), 256, 0, stream>>>(lin_q, lin_k, lin_v,
                                            cwq, cbq, cwk, cbk, cwv, cbv, qb, kb, vb);
  kq_kernel<<<N_ / 8, 512, 0, stream>>>(qb, kb, kqd);
  scan_kernel<<<dim3(64, 8), 512, 0, stream>>>(qb, kb, vb, alpha, beta, kqd, gdn);
  norm_gate<<<N_, 256, 0, stream>>>(gdn, lin_g, nw, h);
  gemm_bt<<<gg, 256, 0, stream>>>(h, wo_b, bo, (float*)d_out);
}

// Round 5
// 711.797 us; speedup vs baseline: 2.9172x; 2.0202x over previous
//
#include <hip/hip_runtime.h>
#include <math.h>

typedef unsigned short u16;
typedef unsigned int u32;
typedef short short8 __attribute__((ext_vector_type(8)));
typedef float f32x4 __attribute__((ext_vector_type(4)));

#define B_ 8
#define S_ 2048
#define D_ 512
#define N_ (B_ * S_)
#define ND_ ((size_t)N_ * D_)
#define CC_ 32              // chunk length
#define NC_ (S_ / CC_)      // 64 chunks
#define SV_ 16              // v-rows per scan block

__device__ __forceinline__ u16 f2bf(float f) {
  union { float f; u32 i; } v; v.f = f;
  u32 i = v.i;
  i += 0x7FFFu + ((i >> 16) & 1u);   // round-to-nearest-even
  return (u16)(i >> 16);
}
__device__ __forceinline__ float sigm(float x) { return 1.0f / (1.0f + expf(-x)); }

// ---------------------------------------------------------------------------
// f32 -> bf16 conversion
// ---------------------------------------------------------------------------
__global__ __launch_bounds__(256) void cvt_bf16(const float* __restrict__ s,
                                                u16* __restrict__ d, int n)
{
  const int i = (blockIdx.x * 256 + threadIdx.x) * 4;
  if (i < n) {
    const float4 v = *(const float4*)(s + i);
    ushort4 o;
    o.x = f2bf(v.x); o.y = f2bf(v.y); o.z = f2bf(v.z); o.w = f2bf(v.w);
    *(ushort4*)(d + i) = o;
  }
}

// ---------------------------------------------------------------------------
// GEMM: out[m,n] = sum_k A[m,k]*W[n,k] + bias[n]; bf16 in, f32 out.
// ---------------------------------------------------------------------------
__global__ __launch_bounds__(256) void gemm_bt(
    const u16* __restrict__ A, const u16* __restrict__ W,
    const float* __restrict__ bias, float* __restrict__ out)
{
  __shared__ u16 As[128 * 40];
  __shared__ u16 Bs[128 * 40];
  const int tid = threadIdx.x;
  const int lane = tid & 63, wave = tid >> 6;
  const int wm = (wave >> 1) * 64, wn = (wave & 1) * 64;
  const int l15 = lane & 15, quad = lane >> 4;
  const int m0 = blockIdx.x * 128, n0 = blockIdx.y * 128;
  const int r0 = tid >> 2;
  const int kc0 = (tid & 3) * 8;

  f32x4 acc[4][4];
#pragma unroll
  for (int i = 0; i < 4; i++)
#pragma unroll
    for (int j = 0; j < 4; j++) acc[i][j] = (f32x4){0.f, 0.f, 0.f, 0.f};

  for (int k0 = 0; k0 < 512; k0 += 32) {
    uint4 a0 = *(const uint4*)(A + (size_t)(m0 + r0) * 512 + k0 + kc0);
    uint4 a1 = *(const uint4*)(A + (size_t)(m0 + r0 + 64) * 512 + k0 + kc0);
    uint4 b0 = *(const uint4*)(W + (size_t)(n0 + r0) * 512 + k0 + kc0);
    uint4 b1 = *(const uint4*)(W + (size_t)(n0 + r0 + 64) * 512 + k0 + kc0);
    __syncthreads();
    *(uint4*)(As + r0 * 40 + kc0) = a0;
    *(uint4*)(As + (r0 + 64) * 40 + kc0) = a1;
    *(uint4*)(Bs + r0 * 40 + kc0) = b0;
    *(uint4*)(Bs + (r0 + 64) * 40 + kc0) = b1;
    __syncthreads();
    short8 af[4], bf[4];
#pragma unroll
    for (int mt = 0; mt < 4; mt++) af[mt] = *(const short8*)(As + (wm + mt * 16 + l15) * 40 + quad * 8);
#pragma unroll
    for (int nt = 0; nt < 4; nt++) bf[nt] = *(const short8*)(Bs + (wn + nt * 16 + l15) * 40 + quad * 8);
#pragma unroll
    for (int mt = 0; mt < 4; mt++)
#pragma unroll
      for (int nt = 0; nt < 4; nt++)
        acc[mt][nt] = __builtin_amdgcn_mfma_f32_16x16x32_bf16(af[mt], bf[nt], acc[mt][nt], 0, 0, 0);
  }
#pragma unroll
  for (int mt = 0; mt < 4; mt++) {
#pragma unroll
    for (int nt = 0; nt < 4; nt++) {
      const int col = n0 + wn + nt * 16 + l15;
      const float bcol = bias[col];
#pragma unroll
      for (int r = 0; r < 4; r++) {
        const int row = m0 + wm + mt * 16 + quad * 4 + r;
        out[(size_t)row * 512 + col] = acc[mt][nt][r] + bcol;
      }
    }
  }
}

// ---------------------------------------------------------------------------
// alpha/beta
// ---------------------------------------------------------------------------
__global__ __launch_bounds__(256) void ab_kernel(
    const float* __restrict__ x, const float* __restrict__ Wa, const float* __restrict__ ba,
    const float* __restrict__ Wb, const float* __restrict__ bb,
    float* __restrict__ alpha, float* __restrict__ beta)
{
  const int lane = threadIdx.x & 63, wave = threadIdx.x >> 6;
  const int row = blockIdx.x * 4 + wave;
  const float4 x0 = *(const float4*)(x + (size_t)row * 512 + lane * 8);
  const float4 x1 = *(const float4*)(x + (size_t)row * 512 + lane * 8 + 4);
  const float4 a0 = *(const float4*)(Wa + lane * 8);
  const float4 a1 = *(const float4*)(Wa + lane * 8 + 4);
  const float4 b0 = *(const float4*)(Wb + lane * 8);
  const float4 b1 = *(const float4*)(Wb + lane * 8 + 4);
  float da = x0.x*a0.x + x0.y*a0.y + x0.z*a0.z + x0.w*a0.w
           + x1.x*a1.x + x1.y*a1.y + x1.z*a1.z + x1.w*a1.w;
  float db = x0.x*b0.x + x0.y*b0.y + x0.z*b0.z + x0.w*b0.w
           + x1.x*b1.x + x1.y*b1.y + x1.z*b1.z + x1.w*b1.w;
#pragma unroll
  for (int m = 32; m >= 1; m >>= 1) { da += __shfl_xor(da, m, 64); db += __shfl_xor(db, m, 64); }
  if (lane == 0) {
    alpha[row] = sigm(da + ba[0]);
    beta[row]  = sigm(db + bb[0]);
  }
}

// ---------------------------------------------------------------------------
// causal depthwise conv (k=4) + SiLU (+ L2 norm for q,k -> bf16; v -> f32)
// ---------------------------------------------------------------------------
__global__ __launch_bounds__(256) void conv_act(
    const float* __restrict__ lq, const float* __restrict__ lk, const float* __restrict__ lv,
    const float* __restrict__ cwq, const float* __restrict__ cbq,
    const float* __restrict__ cwk, const float* __restrict__ cbk,
    const float* __restrict__ cwv, const float* __restrict__ cbv,
    u16* __restrict__ oq, u16* __restrict__ ok, float* __restrict__ ov)
{
  __shared__ float red[4];
  const int row = blockIdx.x;
  const int z = blockIdx.y;
  const int b = row / S_, t = row - b * S_;
  const float* lin = (z == 0) ? lq : (z == 1) ? lk : lv;
  const float* cw = (z == 0) ? cwq : (z == 1) ? cwk : cwv;
  const float* cb = (z == 0) ? cbq : (z == 1) ? cbk : cbv;
  const int tid = threadIdx.x;
  float s[2]; float ssq = 0.f;
#pragma unroll
  for (int e = 0; e < 2; e++) {
    const int ch = tid + e * 256;
    float acc = cb[ch];
#pragma unroll
    for (int tau = 0; tau < 4; tau++) {
      const int tt = t - 3 + tau;
      if (tt >= 0) acc = fmaf(lin[(size_t)(b * S_ + tt) * D_ + ch], cw[ch * 4 + tau], acc);
    }
    const float sv = acc * sigm(acc);
    s[e] = sv; ssq = fmaf(sv, sv, ssq);
  }
  if (z < 2) {
    float v = ssq;
#pragma unroll
    for (int m = 32; m >= 1; m >>= 1) v += __shfl_xor(v, m, 64);
    if ((tid & 63) == 0) red[tid >> 6] = v;
    __syncthreads();
    const float tot = red[0] + red[1] + red[2] + red[3];
    const float scale = 1.0f / fmaxf(sqrtf(tot), 1e-12f);
    u16* outp = (z == 0) ? oq : ok;
    outp[(size_t)row * D_ + tid] = f2bf(s[0] * scale);
    outp[(size_t)row * D_ + tid + 256] = f2bf(s[1] * scale);
  } else {
    ov[(size_t)row * D_ + tid] = s[0];
    ov[(size_t)row * D_ + tid + 256] = s[1];
  }
}

// ---------------------------------------------------------------------------
// transpose kh [b,t,ch] -> khT [b,ch,t]  (bf16), 64x64 tiles
// ---------------------------------------------------------------------------
__global__ __launch_bounds__(256) void transpose_k(
    const u16* __restrict__ kh, u16* __restrict__ khT)
{
  __shared__ u16 T[64][68];
  const int b = blockIdx.z;
  const int t0 = blockIdx.x * 64;
  const int c0 = blockIdx.y * 64;
  const int tid = threadIdx.x;
  const int tr = tid >> 4;
  const int c4 = (tid & 15) * 4;
#pragma unroll
  for (int i = 0; i < 4; i++) {
    const int t = tr + i * 16;
    ushort4 v = *(const ushort4*)(kh + ((size_t)(b * S_ + t0 + t)) * 512 + c0 + c4);
    T[c4 + 0][t] = v.x; T[c4 + 1][t] = v.y; T[c4 + 2][t] = v.z; T[c4 + 3][t] = v.w;
  }
  __syncthreads();
#pragma unroll
  for (int i = 0; i < 4; i++) {
    const int ch = tr + i * 16;
    ushort4 v = *(const ushort4*)&T[ch][c4];
    *(ushort4*)(khT + ((size_t)(b * 512 + c0 + ch)) * S_ + t0 + c4) = v;
  }
}

// ---------------------------------------------------------------------------
// prepass: per (b,chunk) build X=(I+M)^-1 (bf16), A matrix (bf16), gamma tables
// M_ts = b_t e^{lg_t-lg_s} (k_t.k_s) (s<t);  A_ts = (q_t.k_s) e^{lg_t-lg_s} (s<=t)
// grid: 512 blocks (b*64+c), 256 threads.
// ---------------------------------------------------------------------------
__global__ __launch_bounds__(256) void prepass(
    const u16* __restrict__ kh, const u16* __restrict__ qh,
    const float* __restrict__ alpha, const float* __restrict__ beta,
    u16* __restrict__ Xg, u16* __restrict__ Ag, float* __restrict__ gg)
{
  __shared__ float KK[32][33];
  __shared__ float QK[32][33];
  __shared__ float Ml[32][33];
  __shared__ float Xs[32][33];
  __shared__ float lg[32], cum[32], bet[32];
  const int bc = blockIdx.x;
  const int b = bc >> 6, c = bc & 63;
  const int t0 = c * CC_;
  const int tid = threadIdx.x, lane = tid & 63, w = tid >> 6;
  const int l15 = lane & 15, quad = lane >> 4;
  const size_t rb = (size_t)b * S_ + t0;

  if (tid < 32) { lg[tid] = logf(alpha[b * S_ + t0 + tid]); bet[tid] = beta[b * S_ + t0 + tid]; }
  __syncthreads();
  if (tid < 32) {
    float s = 0.f;
    for (int u = 0; u <= tid; u++) s += lg[u];
    cum[tid] = s;
  }
  // KK^T and QK^T quadrants (independent of cum)
  const int mi = w >> 1, ni = w & 1;
  f32x4 ck = (f32x4){0.f,0.f,0.f,0.f}, cq = ck;
#pragma unroll
  for (int kt = 0; kt < 16; kt++) {
    const int kc = kt * 32 + quad * 8;
    short8 afk = *(const short8*)(kh + (rb + mi * 16 + l15) * 512 + kc);
    short8 afq = *(const short8*)(qh + (rb + mi * 16 + l15) * 512 + kc);
    short8 bk  = *(const short8*)(kh + (rb + ni * 16 + l15) * 512 + kc);
    ck = __builtin_amdgcn_mfma_f32_16x16x32_bf16(afk, bk, ck, 0, 0, 0);
    cq = __builtin_amdgcn_mfma_f32_16x16x32_bf16(afq, bk, cq, 0, 0, 0);
  }
#pragma unroll
  for (int r = 0; r < 4; r++) {
    KK[mi * 16 + quad * 4 + r][ni * 16 + l15] = ck[r];
    QK[mi * 16 + quad * 4 + r][ni * 16 + l15] = cq[r];
  }
  __syncthreads();
  if (tid < 32) {
    gg[(size_t)bc * 64 + tid] = expf(cum[tid]);
    gg[(size_t)bc * 64 + 32 + tid] = expf(cum[31] - cum[tid]);
  }
#pragma unroll
  for (int rep = 0; rep < 4; rep++) {
    const int e = tid + rep * 256;
    const int t = e >> 5, s = e & 31;
    const float er = expf(cum[t] - cum[s]);
    Ml[t][s] = (s < t) ? bet[t] * er * KK[t][s] : 0.f;
    Ag[(size_t)bc * 1024 + t * 32 + s] = (s <= t) ? f2bf(QK[t][s] * er) : (u16)0;
  }
  __syncthreads();
  if (w == 0 && lane < 32) {
    const int j = lane;
    Xs[0][j] = (j == 0) ? 1.f : 0.f;
    for (int t = 1; t < 32; t++) {
      float a = (t == j) ? 1.f : 0.f;
      for (int u = 0; u < t; u++) a = fmaf(-Ml[t][u], Xs[u][j], a);
      Xs[t][j] = a;
    }
  }
  __syncthreads();
#pragma unroll
  for (int rep = 0; rep < 4; rep++) {
    const int e = tid + rep * 256;
    const int t = e >> 5, s = e & 31;
    Xg[(size_t)bc * 1024 + t * 32 + s] = f2bf(Xs[t][s]);
  }
}

// ---------------------------------------------------------------------------
// chunked gated-delta scan. Block = 256 thr (4 waves), owns SV_=16 v-rows of S.
// State S^T slice (512k x 16v) in MFMA C-layout accs: wave w owns krows
// [w*128, w*128+128): 8 m-tiles x f32x4. grid (32 slices, 8 batches).
// ---------------------------------------------------------------------------
__global__ __launch_bounds__(256) void scan_chunk(
    const u16* __restrict__ kh, const u16* __restrict__ qh,
    const u16* __restrict__ khT, const float* __restrict__ vb,
    const float* __restrict__ beta, const u16* __restrict__ Xg,
    const u16* __restrict__ Ag, const float* __restrict__ gg,
    float* __restrict__ gdn)
{
  __shared__ u16 S_A[16 * 520];       // S[v][k] bf16 (slice: all 512 k)
  __shared__ float PA[4][32][16];     // G_A^T partials [wave][s][v]
  __shared__ float PB[4][32][16];
  __shared__ u16 R_T[16 * 40];        // Btilde*R^T [v][s]
  __shared__ u16 Ct_T[16 * 40];       // C~^T [v][s]
  __shared__ u16 Cr_T[16 * 40];       // C~^T * (gC/gs)
  __shared__ float OB[32][16];        // gamma_t * G_B^T reduced  [t][v]
  __shared__ float O_s[32][20];       // staged output [t][v]
  __shared__ float gam[32], grc[32];
  const int b = blockIdx.y;
  const int iv0 = blockIdx.x * SV_;
  const int tid = threadIdx.x, lane = tid & 63, w = tid >> 6;
  const int l15 = lane & 15, quad = lane >> 4;
  const size_t bS = (size_t)b * S_;

  f32x4 acc[8];
#pragma unroll
  for (int mt = 0; mt < 8; mt++) acc[mt] = (f32x4){0.f, 0.f, 0.f, 0.f};

#pragma unroll 1
  for (int c = 0; c < NC_; c++) {
    const int t0 = c * CC_;
    const int bc = b * 64 + c;
    // ---- phase A: gamma preload + dump S (bf16) to LDS ----
    if (tid < 32) { gam[tid] = gg[(size_t)bc * 64 + tid]; grc[tid] = gg[(size_t)bc * 64 + 32 + tid]; }
#pragma unroll
    for (int mt = 0; mt < 8; mt++) {
      ushort4 p;
      p.x = f2bf(acc[mt][0]); p.y = f2bf(acc[mt][1]);
      p.z = f2bf(acc[mt][2]); p.w = f2bf(acc[mt][3]);
      *(ushort4*)&S_A[l15 * 520 + w * 128 + mt * 16 + quad * 4] = p;
    }
    __syncthreads();
    // ---- phase B: G_A^T, G_B^T partials over this wave's 128 k-cols ----
    f32x4 ga[2], gb[2];
    ga[0] = ga[1] = gb[0] = gb[1] = (f32x4){0.f, 0.f, 0.f, 0.f};
#pragma unroll
    for (int kt = 0; kt < 4; kt++) {
      const int kc = w * 128 + kt * 32 + quad * 8;
      short8 af = *(const short8*)&S_A[l15 * 520 + kc];
#pragma unroll
      for (int nt = 0; nt < 2; nt++) {
        const size_t rowk = (bS + t0 + nt * 16 + l15) * 512 + kc;
        short8 bk = *(const short8*)(kh + rowk);
        short8 bq = *(const short8*)(qh + rowk);
        ga[nt] = __builtin_amdgcn_mfma_f32_16x16x32_bf16(af, bk, ga[nt], 0, 0, 0);
        gb[nt] = __builtin_amdgcn_mfma_f32_16x16x32_bf16(af, bq, gb[nt], 0, 0, 0);
      }
    }
#pragma unroll
    for (int nt = 0; nt < 2; nt++) {
      const int s = nt * 16 + l15;
      *(f32x4*)&PA[w][s][quad * 4] = ga[nt];
      *(f32x4*)&PB[w][s][quad * 4] = gb[nt];
    }
    __syncthreads();
    // ---- phase C: reduce partials, build R~^T (bf16) and OB; flush prev O ----
#pragma unroll
    for (int rep = 0; rep < 2; rep++) {
      const int e = tid + rep * 256;
      const int s = e >> 4, v = e & 15;
      const float sa = PA[0][s][v] + PA[1][s][v] + PA[2][s][v] + PA[3][s][v];
      const float sb = PB[0][s][v] + PB[1][s][v] + PB[2][s][v] + PB[3][s][v];
      const float g = gam[s];
      const float bt = beta[bS + t0 + s];
      const float vv = vb[(bS + t0 + s) * 512 + iv0 + v];
      R_T[v * 40 + s] = f2bf(bt * (vv - g * sa));
      OB[s][v] = g * sb;
    }
    if (c > 0) {
#pragma unroll
      for (int rep = 0; rep < 2; rep++) {
        const int e = tid + rep * 256;
        const int s = e >> 4, v = e & 15;
        gdn[(bS + t0 - CC_ + s) * 512 + iv0 + v] = O_s[s][v];
      }
    }
    __syncthreads();
    // ---- phase D: wave0 solves C~^T = R~^T X^T ----
    if (w == 0) {
      short8 af = *(const short8*)&R_T[l15 * 40 + quad * 8];
      f32x4 cc[2];
      cc[0] = cc[1] = (f32x4){0.f, 0.f, 0.f, 0.f};
#pragma unroll
      for (int nt = 0; nt < 2; nt++) {
        short8 bx = *(const short8*)(Xg + (size_t)bc * 1024 + (nt * 16 + l15) * 32 + quad * 8);
        cc[nt] = __builtin_amdgcn_mfma_f32_16x16x32_bf16(af, bx, cc[nt], 0, 0, 0);
      }
#pragma unroll
      for (int nt = 0; nt < 2; nt++) {
        const int t = nt * 16 + l15;
        const float gr = grc[t];
#pragma unroll
        for (int r = 0; r < 4; r++) {
          Ct_T[(quad * 4 + r) * 40 + t] = f2bf(cc[nt][r]);
          Cr_T[(quad * 4 + r) * 40 + t] = f2bf(cc[nt][r] * gr);
        }
      }
    }
    __syncthreads();
    // ---- phase F: state update GEMM (all waves); wave0 also O GEMM ----
    const float gC = gam[31];
#pragma unroll
    for (int mt = 0; mt < 8; mt++) {
      const int kr = w * 128 + mt * 16 + l15;
      short8 at = *(const short8*)(khT + ((size_t)(b * 512 + kr)) * S_ + t0 + quad * 8);
      short8 bcf = *(const short8*)&Cr_T[l15 * 40 + quad * 8];
      acc[mt] = acc[mt] * gC;
      acc[mt] = __builtin_amdgcn_mfma_f32_16x16x32_bf16(at, bcf, acc[mt], 0, 0, 0);
    }
    if (w == 0) {
      short8 af = *(const short8*)&Ct_T[l15 * 40 + quad * 8];
#pragma unroll
      for (int nt = 0; nt < 2; nt++) {
        const int t = nt * 16 + l15;
        f32x4 oo = *(const f32x4*)&OB[t][quad * 4];
        short8 ba = *(const short8*)(Ag + (size_t)bc * 1024 + t * 32 + quad * 8);
        oo = __builtin_amdgcn_mfma_f32_16x16x32_bf16(af, ba, oo, 0, 0, 0);
        *(f32x4*)&O_s[t][quad * 4] = oo;
      }
    }
  }
  __syncthreads();
  // final O flush (chunk NC_-1)
#pragma unroll
  for (int rep = 0; rep < 2; rep++) {
    const int e = tid + rep * 256;
    const int s = e >> 4, v = e & 15;
    gdn[(bS + (NC_ - 1) * CC_ + s) * 512 + iv0 + v] = O_s[s][v];
  }
}

// ---------------------------------------------------------------------------
// zero-centered rmsnorm * norm_w * silu(gate) -> bf16 h
// ---------------------------------------------------------------------------
__global__ __launch_bounds__(256) void norm_gate(
    const float* __restrict__ gdn, const float* __restrict__ lg,
    const float* __restrict__ nw, u16* __restrict__ h)
{
  __shared__ float red[8];
  const int row = blockIdx.x, tid = threadIdx.x;
  const size_t base = (size_t)row * D_;
  const float g0 = gdn[base + tid], g1 = gdn[base + tid + 256];
  float sm = g0 + g1;
#pragma unroll
  for (int m = 32; m >= 1; m >>= 1) sm += __shfl_xor(sm, m, 64);
  if ((tid & 63) == 0) red[tid >> 6] = sm;
  __syncthreads();
  const float mean = (red[0] + red[1] + red[2] + red[3]) * (1.0f / 512.0f);
  const float x0 = g0 - mean, x1 = g1 - mean;
  float sq = x0 * x0 + x1 * x1;
#pragma unroll
  for (int m = 32; m >= 1; m >>= 1) sq += __shfl_xor(sq, m, 64);
  if ((tid & 63) == 0) red[4 + (tid >> 6)] = sq;
  __syncthreads();
  const float var = (red[4] + red[5] + red[6] + red[7]) * (1.0f / 512.0f);
  const float rst = rsqrtf(var + 1e-5f);
  const float gl0 = lg[base + tid];
  h[base + tid] = f2bf(x0 * rst * nw[tid] * (gl0 * sigm(gl0)));
  const float gl1 = lg[base + tid + 256];
  h[base + tid + 256] = f2bf(x1 * rst * nw[tid + 256] * (gl1 * sigm(gl1)));
}

// ---------------------------------------------------------------------------
extern "C" void kernel_launch(void* const* d_in, const int* in_sizes, int n_in,
                              void* d_out, int out_size, void* d_ws, size_t ws_size,
                              hipStream_t stream)
{
  const float* x   = (const float*)d_in[0];
  const float* Wq  = (const float*)d_in[1];
  const float* bq  = (const float*)d_in[2];
  const float* Wk  = (const float*)d_in[3];
  const float* bk  = (const float*)d_in[4];
  const float* Wv  = (const float*)d_in[5];
  const float* bv  = (const float*)d_in[6];
  const float* Wa  = (const float*)d_in[7];
  const float* ba  = (const float*)d_in[8];
  const float* Wb  = (const float*)d_in[9];
  const float* bb  = (const float*)d_in[10];
  const float* cwq = (const float*)d_in[11];
  const float* cbq = (const float*)d_in[12];
  const float* cwk = (const float*)d_in[13];
  const float* cbk = (const float*)d_in[14];
  const float* cwv = (const float*)d_in[15];
  const float* cbv = (const float*)d_in[16];
  const float* nw  = (const float*)d_in[17];
  const float* Wg  = (const float*)d_in[18];
  const float* bg  = (const float*)d_in[19];
  const float* Wo  = (const float*)d_in[20];
  const float* bo  = (const float*)d_in[21];

  float* ws    = (float*)d_ws;
  float* lin_q = ws;               // f32; reused as gdn after conv
  float* lin_k = ws + ND_;         // f32; reused as khT/Xg/Ag/gg after conv
  float* lin_v = ws + 2 * ND_;     // f32; reused as h (bf16) after scan
  float* lin_g = ws + 3 * ND_;
  float* vb    = ws + 4 * ND_;
  u16*   qh    = (u16*)(ws + 5 * ND_);   // ND_ u16
  u16*   kh    = qh + ND_;               // ND_ u16
  float* alpha = ws + 6 * ND_;
  float* beta  = alpha + N_;
  u16*   xb    = (u16*)(beta + N_);
  u16*   wq_b  = xb + ND_;
  u16*   wk_b  = wq_b + 512 * 512;
  u16*   wv_b  = wk_b + 512 * 512;
  u16*   wg_b  = wv_b + 512 * 512;
  u16*   wo_b  = wg_b + 512 * 512;

  u16*   khT   = (u16*)lin_k;            // ND_ u16
  u16*   Xg    = khT + ND_;              // 512*1024 u16
  u16*   Ag    = Xg + (size_t)512 * 1024;
  float* gg    = (float*)(Ag + (size_t)512 * 1024);  // 512*64 f32
  float* gdn   = lin_q;
  u16*   h     = (u16*)lin_v;

  const int NW = 512 * 512;
  cvt_bf16<<<(int)(ND_ / 1024), 256, 0, stream>>>(x, xb, (int)ND_);
  cvt_bf16<<<NW / 1024, 256, 0, stream>>>(Wq, wq_b, NW);
  cvt_bf16<<<NW / 1024, 256, 0, stream>>>(Wk, wk_b, NW);
  cvt_bf16<<<NW / 1024, 256, 0, stream>>>(Wv, wv_b, NW);
  cvt_bf16<<<NW / 1024, 256, 0, stream>>>(Wg, wg_b, NW);
  cvt_bf16<<<NW / 1024, 256, 0, stream>>>(Wo, wo_b, NW);

  dim3 gg4(128, 4);
  gemm_bt<<<gg4, 256, 0, stream>>>(xb, wq_b, bq, lin_q);
  gemm_bt<<<gg4, 256, 0, stream>>>(xb, wk_b, bk, lin_k);
  gemm_bt<<<gg4, 256, 0, stream>>>(xb, wv_b, bv, lin_v);
  gemm_bt<<<gg4, 256, 0, stream>>>(xb, wg_b, bg, lin_g);
  ab_kernel<<<N_ / 4, 256, 0, stream>>>(x, Wa, ba, Wb, bb, alpha, beta);
  conv_act<<<dim3(N_, 3), 256, 0, stream>>>(lin_q, lin_k, lin_v,
                                            cwq, cbq, cwk, cbk, cwv, cbv, qh, kh, vb);
  transpose_k<<<dim3(S_ / 64, D_ / 64, B_), 256, 0, stream>>>(kh, khT);
  prepass<<<B_ * NC_, 256, 0, stream>>>(kh, qh, alpha, beta, Xg, Ag, gg);
  scan_chunk<<<dim3(D_ / SV_, B_), 256, 0, stream>>>(kh, qh, khT, vb, beta,
                                                     Xg, Ag, gg, gdn);
  norm_gate<<<N_, 256, 0, stream>>>(gdn, lin_g, nw, h);
  gemm_bt<<<gg4, 256, 0, stream>>>(h, wo_b, bo, (float*)d_out);
}